// Round 4
// baseline (218.330 us; speedup 1.0000x reference)
//
#include <hip/hip_runtime.h>

// SPGG Q-learning step on a 2048x2048 torus — single fused kernel,
// WAVE-PRIVATE LDS tiles, NO __syncthreads.
//
// Round-3 post-mortem: with a block-shared tile + barrier, VALU (35%), LDS
// (~20%) and HBM (28%) phases ran back-to-back (dur ~= sum of pipes, 76us).
// The barrier compiles to s_waitcnt vmcnt(0) lgkmcnt(0) + s_barrier, phase-
// locking all waves. Here each 64-lane wave stages its OWN 7x72 tt tile
// (rows i-3..i+3, cols j0w-4..j0w+67, wrapped) into a private LDS slice;
// wave-internal ds_write->ds_read ordering is enforced by compiler lgkmcnt
// waits — no barrier, waves desync, pipes overlap.
//
// upd (fermi profit) is a pure function of inputs, so each thread recomputes
// its selected neighbor's upd bit-identically (same __f*_rn op sequence).
// exp in double, rounded once. Identical numerics to passing rounds 1-3.

#define LSIDE 2048
#define LMASK 2047
#define LSHIFT 11
#define NCELL (LSIDE * LSIDE)

__global__ __launch_bounds__(256) void spgg_fused(
    const int* __restrict__ tmin,   // type_t_minus
    const int* __restrict__ tt,     // type_t
    const float* __restrict__ Q,    // Q_tensor [N,4]
    const int* __restrict__ ldir,   // learning_direction
    const float* __restrict__ lp,   // learning_probabilities
    float* __restrict__ Qn,         // out: Q_new [N,4]
    float* __restrict__ prof,       // out: profit [N]
    float* __restrict__ t1out)      // out: type_t1 [N]
{
    __shared__ int tile[4][7][72];   // per-wave private slices, 8064 B total

    const int tid = threadIdx.x;
    const int w   = tid >> 6;        // wave id within block
    const int l   = tid & 63;        // lane
    const int idx = blockIdx.x * 256 + tid;
    const int i   = idx >> LSHIFT;
    const int j   = idx & LMASK;
    const int j0w = j & ~63;         // wave's column base (multiple of 64)

    // ---- stage wave-private tt tile: 7 rows x 18 int4 = 126 int4 / 64 lanes.
    // No barrier: only this wave reads tile[w]; lgkmcnt waits order it.
    {
        const int base_row = i - 3;
        const int base_col = j0w - 4;          // multiple of 4 -> aligned int4
#pragma unroll
        for (int p = 0; p < 2; ++p) {
            int k = l + (p << 6);
            if (k < 126) {
                int r = (k * 57) >> 10;        // k/18 for k<128
                int m = k - r * 18;
                int rg = (base_row + r) & LMASK;
                int cg = (base_col + (m << 2)) & LMASK;
                int4 v = *(const int4*)&tt[(rg << LSHIFT) + cg];
                *(int4*)&tile[w][r][m << 2] = v;
            }
        }
    }

    // ---- issue all coalesced own-cell loads early (overlap with staging) ----
    float4 qr = ((const float4*)Q)[idx];
    int    A  = tmin[idx];
    int    dir = ldir[idx];
    float  pv  = lp[idx];

    // dir: 0=left(j-1) 1=right(j+1) 2=up(i-1) 3=down(i+1)
    int di = (dir == 3) - (dir == 2);
    int dj = (dir == 1) - (dir == 0);
    int ni = (i + di) & LMASK;
    int nj = (j + dj) & LMASK;
    int nidx = (ni << LSHIFT) + nj;

    // neighbor gathers (dependent on ldir) — issue before LDS consumption
    float4 qn4 = ((const float4*)Q)[nidx];
    int    An  = tmin[nidx];

    const float KB        = 0.5554f;  // float32(R / 5.0)
    const float ETA       = 0.8f;
    const float ONE_M_ETA = 0.2f;     // float32(1.0 - 0.8)
    const float GAMMA     = 0.8f;

#define M(r, c) (tile[w][r][c] == 1)

    // profit at wave-tile coords (r,c) — exact reference op order.
    auto profit_at = [&](int r, int c) -> float {
        int m_cc = M(r, c);
        int cn_c = m_cc + M(r-1, c) + M(r+1, c) + M(r, c-1) + M(r, c+1);
        int cn_u = M(r-1, c) + M(r-2, c) + m_cc + M(r-1, c-1) + M(r-1, c+1);
        int cn_d = M(r+1, c) + m_cc + M(r+2, c) + M(r+1, c-1) + M(r+1, c+1);
        int cn_l = M(r, c-1) + M(r-1, c-1) + M(r+1, c-1) + M(r, c-2) + m_cc;
        int cn_r = M(r, c+1) + M(r-1, c+1) + M(r+1, c+1) + m_cc + M(r, c+2);
        float b_c = __fmul_rn((float)cn_c, KB);
        float b_u = __fmul_rn((float)cn_u, KB);
        float b_d = __fmul_rn((float)cn_d, KB);
        float b_l = __fmul_rn((float)cn_l, KB);
        float b_r = __fmul_rn((float)cn_r, KB);
        float s0 = __fadd_rn(__fadd_rn(__fadd_rn(__fadd_rn(b_c, b_u), b_d), b_l), b_r);
        float s1 = __fadd_rn(__fadd_rn(__fadd_rn(__fadd_rn(
                       __fsub_rn(b_c, 1.0f), __fsub_rn(b_u, 1.0f)),
                       __fsub_rn(b_d, 1.0f)), __fsub_rn(b_l, 1.0f)),
                       __fsub_rn(b_r, 1.0f));
        return m_cc ? s1 : s0;
    };

    auto upd_of = [&](float profit, float4 q4, int Ax, int Bx) -> float {
        float q0 = (Bx == 0) ? q4.x : q4.z;
        float q1 = (Bx == 0) ? q4.y : q4.w;
        float mx = fmaxf(q0, q1);
        int k = Ax * 2 + Bx;
        float old = (k == 0) ? q4.x : ((k == 1) ? q4.y : ((k == 2) ? q4.z : q4.w));
        float t0 = __fmul_rn(GAMMA, mx);
        float t1 = __fadd_rn(profit, t0);
        float t2 = __fmul_rn(ETA, t1);
        float t3 = __fmul_rn(ONE_M_ETA, old);
        return __fadd_rn(t3, t2);
    };

    const int lr = 3, lc = l + 4;    // own cell in wave tile

    // ---- own cell: profit + Q update ----
    float p_own = profit_at(lr, lc);
    int B = tile[w][lr][lc];
    float upd = upd_of(p_own, qr, A, B);

    int k = A * 2 + B;
    float4 qo;
    qo.x = (k == 0) ? upd : qr.x;
    qo.y = (k == 1) ? upd : qr.y;
    qo.z = (k == 2) ? upd : qr.z;
    qo.w = (k == 3) ? upd : qr.w;
    ((float4*)Qn)[idx] = qo;
    prof[idx] = p_own;

    // ---- fermi: recompute selected neighbor's upd bit-identically ----
    float p_nb = profit_at(lr + di, lc + dj);
    int Bn = tile[w][lr + di][lc + dj];
    float upd_nb = upd_of(p_nb, qn4, An, Bn);

    float e1 = __fsub_rn(upd, upd_nb);
    float e2 = __fmul_rn(e1, 2.0f);          // / K_FERMI(0.5) exactly
    float ex = (float)exp((double)e2);       // correctly-rounded f32 exp
    float W  = __fdiv_rn(1.0f, __fadd_rn(1.0f, ex));
    int sel = (pv <= W) ? Bn : B;
    t1out[idx] = (float)sel;
#undef M
}

extern "C" void kernel_launch(void* const* d_in, const int* in_sizes, int n_in,
                              void* d_out, int out_size, void* d_ws, size_t ws_size,
                              hipStream_t stream) {
    const int*   type_t_minus = (const int*)d_in[0];
    const int*   type_t       = (const int*)d_in[1];
    const float* Q_tensor     = (const float*)d_in[2];
    const int*   ldir         = (const int*)d_in[3];
    const float* lprob        = (const float*)d_in[4];

    float* out   = (float*)d_out;
    float* Qn    = out;                       // [N*4]
    float* t1out = out + (size_t)4 * NCELL;   // [N]
    float* prof  = out + (size_t)5 * NCELL;   // [N]

    const int threads = 256;
    const int blocks  = NCELL / threads;      // 16384
    spgg_fused<<<blocks, threads, 0, stream>>>(type_t_minus, type_t, Q_tensor,
                                               ldir, lprob, Qn, prof, t1out);
}